// Round 9
// baseline (1117.468 us; speedup 1.0000x reference)
//
#include <hip/hip_runtime.h>
#include <hip/hip_bf16.h>

// CharDecoder: T=21, B=4096, H=1024, E=50, V=96
// d_out: scores(T,B,V) fp32 | h_T(B,H) | c_T(B,H)

#define T_STEPS 21
#define BSZ 4096
#define HDIM 1024
#define VOCAB 96
#define EDIM 50

typedef __attribute__((ext_vector_type(8))) short short8;
typedef __attribute__((ext_vector_type(4))) short shortx4;
typedef __attribute__((ext_vector_type(4))) float f32x4;

#define GLL16(g, l)                                                        \
  __builtin_amdgcn_global_load_lds(                                        \
      (const __attribute__((address_space(1))) void*)(g),                  \
      (__attribute__((address_space(3))) void*)(l), 16, 0, 0)

#define ASM_BARRIER() asm volatile("s_barrier" ::: "memory")
#define ASM_VMCNT4() asm volatile("s_waitcnt vmcnt(4)" ::: "memory")
#define ASM_VMCNT0() asm volatile("s_waitcnt vmcnt(0)" ::: "memory")

__device__ __forceinline__ float sigmoidf_fast(float x) {
  return 1.0f / (1.0f + __expf(-x));
}
__device__ __forceinline__ float tanhf_fast(float x) {
  return 2.0f / (1.0f + __expf(-2.0f * x)) - 1.0f;
}
__device__ __forceinline__ float b2f(short s) {
  return __uint_as_float(((unsigned int)(unsigned short)s) << 16);
}

// ---- prep: fp32 -> bf16 weight/state conversion -------------------------
__global__ void prep_convert(const float* __restrict__ Whh_f,
                             const float* __restrict__ Wout_f,
                             const float* __restrict__ h0,
                             __hip_bfloat16* __restrict__ Whh,
                             __hip_bfloat16* __restrict__ Wout,
                             __hip_bfloat16* __restrict__ hb0) {
  int idx = blockIdx.x * 256 + threadIdx.x;
  if (idx < 4 * HDIM * HDIM) {
    Whh[idx] = __float2bfloat16(Whh_f[idx]);
    hb0[idx] = __float2bfloat16(h0[idx]);
  }
  if (idx < VOCAB * HDIM) Wout[idx] = __float2bfloat16(Wout_f[idx]);
}

// ---- prep: Pb[j>>6][v][unit 64][gate 4] (bf16) = emb.W_ih + b_ih + b_hh -
__global__ void prep_ptable(const float* __restrict__ emb,
                            const float* __restrict__ Wih,
                            const float* __restrict__ bih,
                            const float* __restrict__ bhh,
                            __hip_bfloat16* __restrict__ Pb) {
  int idx = blockIdx.x * 256 + threadIdx.x;  // 96*4096
  int v = idx >> 12, g = idx & 4095;         // g = gate*1024 + j
  int gate = g >> 10, j = g & 1023;
  const float* er = emb + v * EDIM;
  const float* wr = Wih + g * EDIM;
  float s = bih[g] + bhh[g];
#pragma unroll 10
  for (int e = 0; e < EDIM; ++e) s += er[e] * wr[e];
  Pb[(size_t)(j >> 6) * 24576 + v * 256 + (j & 63) * 4 + gate] =
      __float2bfloat16(s);
}

// ---- 256x256 LSTM step, BK=32, QUAD-buffered, register read-ahead -------
// Tile: 256 rows x (4 gates x 64 units); grid 256; 8 waves (2M x 4N).
// LDS 4 bufs x 32KB = 128KB. THE change vs R8: A-fragments of tile k+1 are
// ds_read into the ALTERNATE register set DURING tile k's MFMA cluster, so
// the MFMA cluster has NO lgkm dependency on this interval's A-reads (the
// latency chain that every prior version kept on the critical path). Only
// the 4 B-reads stay in-interval; g-outer MFMA order hides bf[1..3].
// Interval k: [barrier; read afNext(k+1) (8) + bf(k) (4); stage tile k+3
//   (4 GLL16) -> buf[(k+3)&3]; setprio(1); 32 MFMA from afCur; setprio(0);
//   vmcnt(4)].
// vmcnt proof (stage-ahead-3): end-of-k outstanding = stage(k+2)[issued
//   k-1] + stage(k+3)[k] = 8; vmcnt(4) proves tile k+2 -> read as afNext
//   at k+1 and bf at k+2. Prologue: stage 0,1,2; vmcnt(4) proves 0,1.
// WAR: stage(k+3) hits buf[(k-1)&3]; its last reads (bf, interval k-1;
//   afNext, interval k-2) retired >=1 barrier before the stage issues.
// Tail: k=29 vmcnt(0) proves tile 31 (stages for 32+ skipped).
// Reg budget: acc 128 + afA/afB 64 + bf 16 + bases ~25 < 256 (lb 512,2).
// a/b offsets collapse to base + mi*512 elems ((La&7) is mi-invariant).

#define TILE_RA(kk, CB, NB, AFC, AFN, RDNEXT, DOSTAGE, VMW)                \
  {                                                                        \
    ASM_BARRIER();                                                         \
    const __hip_bfloat16* bufC =                                           \
        (const __hip_bfloat16*)(smem + (CB) * 32768);                      \
    if (RDNEXT) {                                                          \
      const __hip_bfloat16* bufN =                                         \
          (const __hip_bfloat16*)(smem + (NB) * 32768);                    \
      _Pragma("unroll") for (int mi = 0; mi < 8; ++mi)                     \
          AFN[mi] = *(const short8*)&bufN[a_base + mi * 512];              \
    }                                                                      \
    short8 bf[4];                                                          \
    _Pragma("unroll") for (int g = 0; g < 4; ++g)                          \
        bf[g] = *(const short8*)&bufC[b_base + g * 512];                   \
    if (DOSTAGE) {                                                         \
      GLL16(hprev + aSrc[0] + ((kk) + 3) * 32,                             \
            smem + (((kk) + 3) & 3) * 32768 + aDst0);                      \
      GLL16(hprev + aSrc[1] + ((kk) + 3) * 32,                             \
            smem + (((kk) + 3) & 3) * 32768 + aDst1);                      \
      GLL16(Whh + bSrc[0] + ((kk) + 3) * 32,                               \
            smem + (((kk) + 3) & 3) * 32768 + bDst0);                      \
      GLL16(Whh + bSrc[1] + ((kk) + 3) * 32,                               \
            smem + (((kk) + 3) & 3) * 32768 + bDst1);                      \
    }                                                                      \
    __builtin_amdgcn_s_setprio(1);                                         \
    _Pragma("unroll") for (int g = 0; g < 4; ++g)                          \
        _Pragma("unroll") for (int mi = 0; mi < 8; ++mi)                   \
            acc[mi][g] = __builtin_amdgcn_mfma_f32_16x16x32_bf16(          \
                AFC[mi], bf[g], acc[mi][g], 0, 0, 0);                      \
    __builtin_amdgcn_s_setprio(0);                                         \
    VMW;                                                                   \
  }

template <bool LAST>
__global__ __launch_bounds__(512, 2) void lstm_step_kernel(
    const int* __restrict__ ids,               // B ints (this t)
    const __hip_bfloat16* __restrict__ hprev,  // B x H
    const __hip_bfloat16* __restrict__ Whh,    // 4H x H (torch order i,f,g,o)
    const __hip_bfloat16* __restrict__ Pb,     // 16 x 96 x 64 x 4 (bf16)
    const float* __restrict__ c_in,            // B x H
    float* __restrict__ c_out,                 // B x H
    __hip_bfloat16* __restrict__ hnext,        // B x H
    float* __restrict__ hf32)                  // B x H (LAST only)
{
  __shared__ __align__(16) char smem[131072];  // 4 x 32KB

  const int tid = threadIdx.x;
  const int wid = tid >> 6;
  const int lane = tid & 63;
  const int wr = wid >> 2;  // 0..1 (M half: 128 rows)
  const int wc = wid & 3;   // 0..3 (N quarter: 16 units x 4 gates)
  const int u16 = lane & 15;
  const int k16q = lane >> 4;

  // XCD swizzle: the 16 jt-blocks sharing an A panel (same mt) on one XCD.
  const int bid = blockIdx.x;
  const int mt = (bid & 7) * 2 + ((bid >> 3) & 1);  // 0..15
  const int jt = bid >> 4;                          // 0..15 (64-unit block)
  const int m0 = mt * 256;

  // ---- fragment read bases (elements); swizzled row-pair layout ----
  // line = row>>1 (128B); S = ((row&1)<<2)|kchunk; slot' = S ^ (line&7).
  // (La&7)==(u16>>1) for all mi -> single base + mi*512 elem immediates.
  int a_base, b_base;
  {
    const int S = ((u16 & 1) << 2) | k16q;
    const int hrow = u16 >> 1;
    a_base = (wr * 64 + hrow) * 64 + (S ^ hrow) * 8;
    b_base = 8192 + (wc * 32 + hrow) * 64 + (S ^ hrow) * 8;
  }

  // ---- staging bases (pre-swizzled global src, linear LDS dest) ----
  size_t aSrc[2], bSrc[2];
  const int aDst0 = wid * 2048;
  const int aDst1 = wid * 2048 + 1024;
  const int bDst0 = 16384 + wid * 2048;
  const int bDst1 = 16384 + wid * 2048 + 1024;
  {
    const int lrow = lane >> 3;
    const int Sp = lane & 7;  // slot' this lane writes
#pragma unroll
    for (int q = 0; q < 2; ++q) {
      const int La = wid * 16 + q * 8 + lrow;
      const int S = Sp ^ (La & 7);
      const int arow = 2 * La + (S >> 2);
      aSrc[q] = (size_t)(m0 + arow) * HDIM + (S & 3) * 8;
      const int n = 2 * La + (S >> 2);  // B row index 0..255
      const int q4 = n >> 6, gate = (n >> 4) & 3, u = n & 15;
      bSrc[q] = (size_t)(gate * HDIM + jt * 64 + q4 * 16 + u) * HDIM +
                (S & 3) * 8;
    }
  }

  // prologue: tiles 0,1,2 -> bufs 0,1,2 (12 GLL16)
#pragma unroll
  for (int t = 0; t < 3; ++t) {
    GLL16(hprev + aSrc[0] + t * 32, smem + t * 32768 + aDst0);
    GLL16(hprev + aSrc[1] + t * 32, smem + t * 32768 + aDst1);
    GLL16(Whh + bSrc[0] + t * 32, smem + t * 32768 + bDst0);
    GLL16(Whh + bSrc[1] + t * 32, smem + t * 32768 + bDst1);
  }
  ASM_VMCNT4();  // 12 -> 4: tiles 0,1 proven; tile 2 in flight
  ASM_BARRIER();

  f32x4 acc[8][4] = {};  // [M-frag][gate]
  short8 afA[8], afB[8];
  {
    const __hip_bfloat16* buf0 = (const __hip_bfloat16*)smem;
#pragma unroll
    for (int mi = 0; mi < 8; ++mi)
      afA[mi] = *(const short8*)&buf0[a_base + mi * 512];
  }

#pragma unroll 1
  for (int kb = 0; kb < 28; kb += 4) {
    TILE_RA(kb + 0, 0, 1, afA, afB, true, true, ASM_VMCNT4());
    TILE_RA(kb + 1, 1, 2, afB, afA, true, true, ASM_VMCNT4());
    TILE_RA(kb + 2, 2, 3, afA, afB, true, true, ASM_VMCNT4());
    TILE_RA(kb + 3, 3, 0, afB, afA, true, true, ASM_VMCNT4());
  }
  TILE_RA(28, 0, 1, afA, afB, true, true, ASM_VMCNT4());
  TILE_RA(29, 1, 2, afB, afA, true, false, ASM_VMCNT0());
  TILE_RA(30, 2, 3, afA, afB, true, false, {});
  TILE_RA(31, 3, 0, afB, afA, false, false, {});
  ASM_BARRIER();  // all waves past tile31 reads before Pb overlay

  // c_in prefetch (overlaps Pb staging); disjoint (row,jcol) tiles.
  const int jcol = jt * 64 + wc * 16 + u16;  // output unit j
  float cpre[8][4];
#pragma unroll
  for (int mi = 0; mi < 8; ++mi)
#pragma unroll
    for (int r = 0; r < 4; ++r)
      cpre[mi][r] = c_in[(size_t)(m0 + wr * 128 + mi * 16 + k16q * 4 + r) *
                             HDIM +
                         jcol];

  // stage bf16 P slice (48 KB) into now-dead LDS (bufs 0 + half of 1).
  {
    const __hip_bfloat16* Pbj = Pb + (size_t)jt * 24576;
#pragma unroll
    for (int i = 0; i < 6; ++i)
      GLL16(Pbj + (wid * 6 + i) * 512 + lane * 8,
            smem + (wid * 6 + i) * 1024);
  }
  ASM_VMCNT0();
  ASM_BARRIER();

  // epilogue: 4 gates of unit jcol contiguous -> one b64 gather per output
  const __hip_bfloat16* sPb = (const __hip_bfloat16*)smem;
  const int uo4 = (wc * 16 + u16) * 4;
  const int rb = m0 + wr * 128 + k16q * 4;
#pragma unroll
  for (int mi = 0; mi < 8; ++mi) {
#pragma unroll
    for (int r = 0; r < 4; ++r) {
      const int row = rb + mi * 16 + r;
      const int id = ids[row];
      const shortx4 pv = *(const shortx4*)&sPb[id * 256 + uo4];
      float iv = acc[mi][0][r] + b2f(pv[0]);
      float fv = acc[mi][1][r] + b2f(pv[1]);
      float gv = acc[mi][2][r] + b2f(pv[2]);
      float ov = acc[mi][3][r] + b2f(pv[3]);
      iv = sigmoidf_fast(iv);
      fv = sigmoidf_fast(fv);
      gv = tanhf_fast(gv);
      ov = sigmoidf_fast(ov);
      const size_t off = (size_t)row * HDIM + jcol;
      const float cc = fv * cpre[mi][r] + iv * gv;
      c_out[off] = cc;
      const float hh = ov * tanhf_fast(cc);
      hnext[off] = __float2bfloat16(hh);
      if (LAST) hf32[off] = hh;
    }
  }
}

// ---- scores: LDS-tiled GEMM, 128 rows x 96 cols per block, BK=128 -------
__global__ __launch_bounds__(256, 2) void scores_kernel(
    const __hip_bfloat16* __restrict__ h,     // rows x H (bf16)
    const __hip_bfloat16* __restrict__ Wout,  // 96 x H
    const float* __restrict__ bout,           // 96
    float* __restrict__ out)                  // rows x 96
{
  __shared__ __align__(16) __hip_bfloat16 sA[128 * 128];  // 32 KB
  __shared__ __align__(16) __hip_bfloat16 sB[96 * 128];   // 24 KB

  const int tid = threadIdx.x;
  const int wave = tid >> 6, lane = tid & 63;
  const int u16 = lane & 15, k16q = lane >> 4;
  const long r0 = (long)blockIdx.x * 128;

  f32x4 acc[2][6] = {};  // wave: 32 rows x 96 cols

  const int srow4 = lane >> 4;
  const int sslot = lane & 15;

  for (int k0 = 0; k0 < HDIM; k0 += 128) {
#pragma unroll
    for (int i = 0; i < 8; ++i) {  // A: 32 rows/wave
      int row = wave * 32 + i * 4 + srow4;
      int gg = sslot ^ (row & 15);
      GLL16(h + (r0 + row) * HDIM + k0 + gg * 8,
            &sA[(wave * 32 + i * 4) * 128]);
    }
#pragma unroll
    for (int i = 0; i < 6; ++i) {  // B: 24 rows/wave
      int row = wave * 24 + i * 4 + srow4;
      int gg = sslot ^ (row & 15);
      GLL16(Wout + (size_t)row * HDIM + k0 + gg * 8,
            &sB[(wave * 24 + i * 4) * 128]);
    }
    __syncthreads();
#pragma unroll
    for (int kk = 0; kk < 128; kk += 32) {
      const int sl = (((kk >> 3) + k16q) ^ u16) * 8;
      short8 af[2], bf[6];
#pragma unroll
      for (int mi = 0; mi < 2; ++mi)
        af[mi] = *(const short8*)&sA[(wave * 32 + mi * 16 + u16) * 128 + sl];
#pragma unroll
      for (int ni = 0; ni < 6; ++ni)
        bf[ni] = *(const short8*)&sB[(ni * 16 + u16) * 128 + sl];
#pragma unroll
      for (int mi = 0; mi < 2; ++mi)
#pragma unroll
        for (int ni = 0; ni < 6; ++ni)
          acc[mi][ni] = __builtin_amdgcn_mfma_f32_16x16x32_bf16(
              af[mi], bf[ni], acc[mi][ni], 0, 0, 0);
    }
    __syncthreads();
  }

#pragma unroll
  for (int ni = 0; ni < 6; ++ni) {
    int v = ni * 16 + u16;
    float bv = bout[v];
#pragma unroll
    for (int mi = 0; mi < 2; ++mi)
#pragma unroll
      for (int r = 0; r < 4; ++r) {
        long grow = r0 + wave * 32 + mi * 16 + k16q * 4 + r;
        out[grow * VOCAB + v] = acc[mi][ni][r] + bv;
      }
  }
}

extern "C" void kernel_launch(void* const* d_in, const int* in_sizes, int n_in,
                              void* d_out, int out_size, void* d_ws,
                              size_t ws_size, hipStream_t stream) {
  const int* ids = (const int*)d_in[0];
  const float* h0 = (const float*)d_in[1];
  const float* c0 = (const float*)d_in[2];
  const float* emb = (const float*)d_in[3];
  const float* Wih = (const float*)d_in[4];
  const float* Whh_f = (const float*)d_in[5];
  const float* bih = (const float*)d_in[6];
  const float* bhh = (const float*)d_in[7];
  const float* Wout_f = (const float*)d_in[8];
  const float* bout = (const float*)d_in[9];

  float* out = (float*)d_out;
  float* scores = out;                              // T*B*V
  float* hT = out + (size_t)T_STEPS * BSZ * VOCAB;  // B*H
  float* cT = hT + (size_t)BSZ * HDIM;              // B*H

  const size_t BH = (size_t)BSZ * HDIM;
  char* w = (char*)d_ws;
  __hip_bfloat16* Pb = (__hip_bfloat16*)w;   w += (size_t)16 * 24576 * 2;
  __hip_bfloat16* Whh = (__hip_bfloat16*)w;  w += (size_t)4 * HDIM * HDIM * 2;
  __hip_bfloat16* Wout = (__hip_bfloat16*)w; w += (size_t)VOCAB * HDIM * 2;
  __hip_bfloat16* hts = (__hip_bfloat16*)w;  // 22*BH (full) or 2*BH (pingpong)
  size_t base = (size_t)16 * 24576 * 2 + (size_t)4 * HDIM * HDIM * 2 +
                (size_t)VOCAB * HDIM * 2;
  const bool full = ws_size >= base + (size_t)(T_STEPS + 1) * BH * 2;

  prep_convert<<<dim3((4 * HDIM * HDIM + 255) / 256), dim3(256), 0, stream>>>(
      Whh_f, Wout_f, h0, Whh, Wout, hts);
  prep_ptable<<<dim3((VOCAB * 4096) / 256), dim3(256), 0, stream>>>(
      emb, Wih, bih, bhh, Pb);

  for (int t = 0; t < T_STEPS; ++t) {
    __hip_bfloat16* hp = hts + (full ? (size_t)t * BH : (size_t)(t & 1) * BH);
    __hip_bfloat16* hn =
        hts + (full ? (size_t)(t + 1) * BH : (size_t)((t + 1) & 1) * BH);
    const float* cin = (t == 0) ? c0 : cT;
    if (t == T_STEPS - 1) {
      lstm_step_kernel<true><<<dim3(256), dim3(512), 0, stream>>>(
          ids + (size_t)t * BSZ, hp, Whh, Pb, cin, cT, hn, hT);
    } else {
      lstm_step_kernel<false><<<dim3(256), dim3(512), 0, stream>>>(
          ids + (size_t)t * BSZ, hp, Whh, Pb, cin, cT, hn, nullptr);
    }
    if (!full) {
      scores_kernel<<<dim3(BSZ / 128), dim3(256), 0, stream>>>(
          hn, Wout, bout, scores + (size_t)t * BSZ * VOCAB);
    }
  }
  if (full) {
    scores_kernel<<<dim3(T_STEPS * BSZ / 128), dim3(256), 0, stream>>>(
        hts + BH, Wout, bout, scores);
  }
}